// Round 3
// baseline (328.994 us; speedup 1.0000x reference)
//
#include <hip/hip_runtime.h>
#include <stdint.h>

typedef unsigned short u16;
typedef unsigned int u32;
typedef __attribute__((ext_vector_type(8))) __bf16 bf16x8;
typedef __attribute__((ext_vector_type(4))) float f32x4;

#define M_TOT 16384   // B*N tokens
#define DIMX  1024

// RNE float->bf16 (finite inputs only)
__device__ __forceinline__ u16 f2b(float f) {
  u32 u = __builtin_bit_cast(u32, f);
  u32 r = (u + 0x7fffu + ((u >> 16) & 1u)) >> 16;
  return (u16)r;
}

__device__ __forceinline__ void gl2lds16(const void* g, void* l) {
  __builtin_amdgcn_global_load_lds((const __attribute__((address_space(1))) void*)g,
                                   (__attribute__((address_space(3))) void*)l,
                                   16, 0, 0);
}

// ---------------- RMSNorm ----------------
__global__ __launch_bounds__(256) void k_rms(const float* __restrict__ x,
                                             const float* __restrict__ gamma,
                                             u16* __restrict__ xn) {
  int row = blockIdx.x;
  int t = threadIdx.x;
  const float4* xr = (const float4*)(x + (size_t)row * DIMX);
  float4 v = xr[t];
  float ss = v.x * v.x + v.y * v.y + v.z * v.z + v.w * v.w;
#pragma unroll
  for (int o = 32; o > 0; o >>= 1) ss += __shfl_xor(ss, o, 64);
  __shared__ float wss[4];
  int w = t >> 6;
  if ((t & 63) == 0) wss[w] = ss;
  __syncthreads();
  float tot = wss[0] + wss[1] + wss[2] + wss[3];
  float scale = 32.0f / fmaxf(sqrtf(tot), 1e-12f);
  float4 g = ((const float4*)gamma)[t];
  ushort4 o4;
  o4.x = f2b(v.x * scale * g.x);
  o4.y = f2b(v.y * scale * g.y);
  o4.z = f2b(v.z * scale * g.z);
  o4.w = f2b(v.w * scale * g.w);
  ((ushort4*)xn)[(size_t)row * 256 + t] = o4;
}

// ---------------- transpose-cast ----------------
__global__ __launch_bounds__(256) void k_castT(const float* __restrict__ in,
                                               u16* __restrict__ out, int Rr, int Cc) {
  __shared__ float tile[32][33];
  int c0 = blockIdx.x * 32, r0 = blockIdx.y * 32;
  int tx = threadIdx.x, ty = threadIdx.y;
#pragma unroll
  for (int i = 0; i < 4; i++)
    tile[ty + i * 8][tx] = in[(size_t)(r0 + ty + i * 8) * Cc + c0 + tx];
  __syncthreads();
#pragma unroll
  for (int i = 0; i < 4; i++)
    out[(size_t)(c0 + ty + i * 8) * Rr + r0 + tx] = f2b(tile[tx][ty + i * 8]);
}

// ---------------- 256x256 8-wave GEMM core, BK=64, m201 schedule ----------------
// LDS: [buf(2)][A0,A1,B0,B1][128x64 u16] = 128 KiB.
// Staging runs 1.75 K-tiles ahead, recycling already-read regions of the
// CURRENT buffer:  P0(t): A1(t+1)->nb;  P1(t): A0(t+2)->bo;
//                  P2(t): B0(t+2)->bo;  P3(t): B1(t+2)->bo.
// ONE vmcnt(6) per K-tile at P3-end: in-flight peaks at 14 loads; drains the
// 8 loads of tile t+1 (issued 3-7 phases earlier) leaving 6 (= 3 halves of
// t+2).  WAR: each region's last ds_read completes before that phase's
// barrier-2 (per-wave lgkmcnt(0) precedes MFMA precedes barrier-2); the
// overwriting stage issues >=2 barriers later.  RAW: per-wave vmcnt(6) +
// barrier => all waves' DMA for tile t+1 globally complete before P0(t+1).
// Phase = {ds_reads; stage; barrier; lgkmcnt(0); setprio; 16 MFMA; setprio;
// barrier}  (P3 has no reads; single barrier after vmcnt).
// Slot swizzle s = chunk ^ (row&7) on BOTH source (pre-swizzled global addr,
// linear LDS dest) and ds_read (involution) -> conflict-free b128 reads.

template<bool SWAP>
__device__ __forceinline__ f32x4 mf(bf16x8 a, bf16x8 b, f32x4 c) {
  return SWAP ? __builtin_amdgcn_mfma_f32_16x16x32_bf16(b, a, c, 0, 0, 0)
              : __builtin_amdgcn_mfma_f32_16x16x32_bf16(a, b, c, 0, 0, 0);
}

// stage one 128x64 half-tile (16 KiB): 2 x gl2lds16 per thread (512 thr)
__device__ __forceinline__ void stage_half(const u16* __restrict__ g,
                                           u16* dst, int t, int k0) {
#pragma unroll
  for (int r = 0; r < 2; r++) {
    int chunk = r * 512 + t;
    int row = chunk >> 3;
    int cc = (chunk & 7) ^ (row & 7);            // inverse swizzle on source
    gl2lds16(g + (size_t)row * 1024 + (k0 + cc * 8),
             dst + (r * 512 + (t >> 6) * 64) * 8);  // linear, wave-uniform base
  }
}

template<bool SWAP>
__device__ __forceinline__ void gemm_core256(const u16* __restrict__ Ag,
                                             const u16* __restrict__ Bg,
                                             u16* lds, int t, f32x4 (&acc)[8][4]) {
  const int lane = t & 63;
  const int r16 = lane & 15, q = lane >> 4;
  const int s0 = (q ^ (r16 & 7)) * 8;   // u16 off of 8-elem slot, kq=0; kq=1: ^32
  const int wr = (t >> 6) >> 2, wc = (t >> 6) & 3;
  const int arow = wr * 16 + r16;
  const int brow = wc * 16 + r16;

  // prologue: tile 0 (4 halves) then tile 1 {A0,B0,B1}; drain tile 0 only.
  stage_half(Ag,              lds + 0,     t, 0);
  stage_half(Bg,              lds + 16384, t, 0);
  stage_half(Bg + 128 * 1024, lds + 24576, t, 0);
  stage_half(Ag + 128 * 1024, lds + 8192,  t, 0);
  stage_half(Ag,              lds + 32768 + 0,     t, 64);
  stage_half(Bg,              lds + 32768 + 16384, t, 64);
  stage_half(Bg + 128 * 1024, lds + 32768 + 24576, t, 64);
  asm volatile("s_waitcnt vmcnt(6)" ::: "memory");
  __builtin_amdgcn_s_barrier();

  bf16x8 af[4][2], bl[2][2], bh[2][2];
#pragma unroll 1
  for (int tt = 0; tt < 16; tt++) {
    const int bo = (tt & 1) << 15;        // buffer u16 offset 0/32768
    const int nb = bo ^ 32768;
    const int k1 = ((tt + 1) & 15) << 6;  // K of tile t+1 (wraps: harmless)
    const int k2 = ((tt + 2) & 15) << 6;  // K of tile t+2 (wraps: harmless)
    const u16* A0 = lds + bo;
    const u16* A1 = lds + bo + 8192;
    const u16* B0 = lds + bo + 16384;
    const u16* B1 = lds + bo + 24576;

    // ---- P0: read a_lo(8)+b_lo(4); stage A1(t+1)->nb; MFMA acc[0..3][0..1] ----
#pragma unroll
    for (int i = 0; i < 4; i++) {
      af[i][0] = *(const bf16x8*)(A0 + (i * 32 + arow) * 64 + s0);
      af[i][1] = *(const bf16x8*)(A0 + (i * 32 + arow) * 64 + (s0 ^ 32));
    }
#pragma unroll
    for (int j = 0; j < 2; j++) {
      bl[j][0] = *(const bf16x8*)(B0 + (j * 64 + brow) * 64 + s0);
      bl[j][1] = *(const bf16x8*)(B0 + (j * 64 + brow) * 64 + (s0 ^ 32));
    }
    stage_half(Ag + 128 * 1024, lds + nb + 8192, t, k1);
    __builtin_amdgcn_s_barrier();
    asm volatile("s_waitcnt lgkmcnt(0)" ::: "memory");
    __builtin_amdgcn_s_setprio(1);
#pragma unroll
    for (int kq = 0; kq < 2; kq++)
#pragma unroll
      for (int i = 0; i < 4; i++)
#pragma unroll
        for (int j = 0; j < 2; j++)
          acc[i][j] = mf<SWAP>(af[i][kq], bl[j][kq], acc[i][j]);
    __builtin_amdgcn_s_setprio(0);
    __builtin_amdgcn_s_barrier();

    // ---- P1: read b_hi(4); stage A0(t+2)->bo; MFMA acc[0..3][2..3] ----
#pragma unroll
    for (int j = 0; j < 2; j++) {
      bh[j][0] = *(const bf16x8*)(B1 + (j * 64 + brow) * 64 + s0);
      bh[j][1] = *(const bf16x8*)(B1 + (j * 64 + brow) * 64 + (s0 ^ 32));
    }
    stage_half(Ag, lds + bo, t, k2);
    __builtin_amdgcn_s_barrier();
    asm volatile("s_waitcnt lgkmcnt(0)" ::: "memory");
    __builtin_amdgcn_s_setprio(1);
#pragma unroll
    for (int kq = 0; kq < 2; kq++)
#pragma unroll
      for (int i = 0; i < 4; i++)
#pragma unroll
        for (int j = 0; j < 2; j++)
          acc[i][2 + j] = mf<SWAP>(af[i][kq], bh[j][kq], acc[i][2 + j]);
    __builtin_amdgcn_s_setprio(0);
    __builtin_amdgcn_s_barrier();

    // ---- P2: read a_hi(8); stage B0(t+2)->bo; MFMA acc[4..7][0..1] ----
#pragma unroll
    for (int i = 0; i < 4; i++) {
      af[i][0] = *(const bf16x8*)(A1 + (i * 32 + arow) * 64 + s0);
      af[i][1] = *(const bf16x8*)(A1 + (i * 32 + arow) * 64 + (s0 ^ 32));
    }
    stage_half(Bg, lds + bo + 16384, t, k2);
    __builtin_amdgcn_s_barrier();
    asm volatile("s_waitcnt lgkmcnt(0)" ::: "memory");
    __builtin_amdgcn_s_setprio(1);
#pragma unroll
    for (int kq = 0; kq < 2; kq++)
#pragma unroll
      for (int i = 0; i < 4; i++)
#pragma unroll
        for (int j = 0; j < 2; j++)
          acc[4 + i][j] = mf<SWAP>(af[i][kq], bl[j][kq], acc[4 + i][j]);
    __builtin_amdgcn_s_setprio(0);
    __builtin_amdgcn_s_barrier();

    // ---- P3: stage B1(t+2)->bo; MFMA acc[4..7][2..3]; vmcnt(6); barrier ----
    stage_half(Bg + 128 * 1024, lds + bo + 24576, t, k2);
    __builtin_amdgcn_s_setprio(1);
#pragma unroll
    for (int kq = 0; kq < 2; kq++)
#pragma unroll
      for (int i = 0; i < 4; i++)
#pragma unroll
        for (int j = 0; j < 2; j++)
          acc[4 + i][2 + j] = mf<SWAP>(af[i][kq], bh[j][kq], acc[4 + i][2 + j]);
    __builtin_amdgcn_s_setprio(0);
    asm volatile("s_waitcnt vmcnt(6)" ::: "memory");   // tile t+1 fully landed
    __builtin_amdgcn_s_barrier();
  }
}

// ---------------- GEMM1 merged q/k/v (256x256 tiles) ----------------
// XCD x owns mt-slab [8x, 8x+8); nt-major within chunk so ~32 concurrent
// blocks touch A 4MB + B 2MB (~L2-resident per XCD).
__global__ __launch_bounds__(512, 2) void k_gemm1(const u16* __restrict__ A,
                                                  const u16* __restrict__ Bt,   // 3072x1024
                                                  u16* __restrict__ qkT,        // 2048x16384
                                                  u16* __restrict__ vmat,       // 16384x1024
                                                  float* __restrict__ sumsq) {  // [4][2048]
  __shared__ u16 lds[8 * 8192];   // 128 KiB
  int l = blockIdx.x;
  int xcd = l & 7, c = l >> 3;        // c in [0,96)
  int mt = xcd * 8 + (c & 7);
  int nt = c >> 3;                    // 0..11
  int m0 = mt * 256, n0 = nt * 256;
  int t = threadIdx.x, lane = t & 63;
  int r16 = lane & 15, q = lane >> 4;
  int wr = (t >> 6) >> 2, wc = (t >> 6) & 3;
  f32x4 acc[8][4] = {};
  if (n0 < 2048) {
    gemm_core256<false>(A + (size_t)m0 * 1024, Bt + (size_t)n0 * 1024, lds, t, acc);
    int b = m0 >> 12;
#pragma unroll
    for (int j = 0; j < 4; j++) {
      int cc = n0 + j * 64 + wc * 16 + r16;
      float colss = 0.f;
#pragma unroll
      for (int i = 0; i < 8; i++) {
        f32x4 a = acc[i][j];
        colss += a.x * a.x + a.y * a.y + a.z * a.z + a.w * a.w;
        int m = m0 + i * 32 + wr * 16 + q * 4;
        ushort4 o4;
        o4.x = f2b(a.x); o4.y = f2b(a.y); o4.z = f2b(a.z); o4.w = f2b(a.w);
        *(ushort4*)(qkT + (size_t)cc * M_TOT + m) = o4;
      }
      colss += __shfl_xor(colss, 16, 64);
      colss += __shfl_xor(colss, 32, 64);
      if (lane < 16) atomicAdd(&sumsq[b * 2048 + cc], colss);
    }
  } else {
    gemm_core256<true>(A + (size_t)m0 * 1024, Bt + (size_t)n0 * 1024, lds, t, acc);
    int vc0 = n0 - 2048;
#pragma unroll
    for (int i = 0; i < 8; i++) {
      int m = m0 + i * 32 + wr * 16 + r16;
#pragma unroll
      for (int j = 0; j < 4; j++) {
        int cc = vc0 + j * 64 + wc * 16 + q * 4;
        f32x4 a = acc[i][j];
        ushort4 o4;
        o4.x = f2b(a.x); o4.y = f2b(a.y); o4.z = f2b(a.z); o4.w = f2b(a.w);
        *(ushort4*)(vmat + (size_t)m * 1024 + cc) = o4;
      }
    }
  }
}

// ---------------- S partials: Spart[split][bh][d][e], wave-private bh, NO atomics ----
__global__ __launch_bounds__(256) void k_attn_s(const u16* __restrict__ qkT,
                                                float* __restrict__ Spart) {
  int g = blockIdx.x, split = blockIdx.y;
  int t = threadIdx.x, lane = t & 63, w = t >> 6;
  int bh = g * 4 + w;
  int b = bh >> 4, h = bh & 15;
  int r16 = lane & 15, q = lane >> 4;
  const u16* qbase = qkT + (size_t)(h * 64) * M_TOT + b * 4096;
  const u16* kbase = qkT + (size_t)(1024 + h * 64) * M_TOT + b * 4096;
  f32x4 acc[4][4] = {};
#pragma unroll
  for (int it = 0; it < 8; it++) {
    int kk = split * 256 + it * 32 + q * 8;
    bf16x8 af[4], bfr[4];
#pragma unroll
    for (int i = 0; i < 4; i++) af[i] = *(const bf16x8*)(qbase + (size_t)(i * 16 + r16) * M_TOT + kk);
#pragma unroll
    for (int j = 0; j < 4; j++) bfr[j] = *(const bf16x8*)(kbase + (size_t)(j * 16 + r16) * M_TOT + kk);
#pragma unroll
    for (int i = 0; i < 4; i++)
#pragma unroll
      for (int j = 0; j < 4; j++)
        acc[i][j] = __builtin_amdgcn_mfma_f32_16x16x32_bf16(bfr[j], af[i], acc[i][j], 0, 0, 0);
  }
  float* Sp = Spart + ((size_t)split * 64 + bh) * 4096;
#pragma unroll
  for (int i = 0; i < 4; i++) {
    int d = i * 16 + r16;
#pragma unroll
    for (int j = 0; j < 4; j++) {
      int e = j * 16 + q * 4;
      *(f32x4*)(Sp + d * 64 + e) = acc[i][j];
    }
  }
}

// ---------------- sum 16 partials + scale + softmax -> PT[bh][e][d] bf16 ----------------
// 256 thr: thread (d = t&63, w = t>>6) owns e in [16w, 16w+16).
__global__ __launch_bounds__(256) void k_softmax(const float* __restrict__ Spart,
                                                 const float* __restrict__ sumsq,
                                                 const float* __restrict__ temp,
                                                 u16* __restrict__ PT) {
  int bh = blockIdx.x;
  int b = bh >> 4, h = bh & 15;
  int t = threadIdx.x;
  int d = t & 63, w = t >> 6;
  int e0 = w * 16;
  __shared__ float rnk[64];
  __shared__ float redm[4][64];
  __shared__ float reds[4][64];
  if (t < 64) rnk[t] = 1.0f / fmaxf(sqrtf(sumsq[b * 2048 + 1024 + h * 64 + t]), 1e-12f);
  __syncthreads();
  float nq = sqrtf(sumsq[b * 2048 + h * 64 + d]);
  float qs = 8.0f * __expf(temp[h]) / fmaxf(nq, 1e-12f);
  const float* Sp = Spart + (size_t)bh * 4096 + d * 64 + e0;
  float vals[16];
#pragma unroll
  for (int e = 0; e < 16; e += 4) {
    f32x4 v = {};
#pragma unroll
    for (int s = 0; s < 16; s++)
      v += *(const f32x4*)(Sp + (size_t)s * 64 * 4096 + e);
    vals[e + 0] = v.x; vals[e + 1] = v.y; vals[e + 2] = v.z; vals[e + 3] = v.w;
  }
  float mx = -3.0e38f;
#pragma unroll
  for (int e = 0; e < 16; e++) {
    float v = vals[e] * qs * rnk[e0 + e];
    vals[e] = v;
    mx = fmaxf(mx, v);
  }
  redm[w][d] = mx;
  __syncthreads();
  float M = fmaxf(fmaxf(redm[0][d], redm[1][d]), fmaxf(redm[2][d], redm[3][d]));
  float s = 0.f;
#pragma unroll
  for (int e = 0; e < 16; e++) {
    float v = __expf(vals[e] - M);
    vals[e] = v;
    s += v;
  }
  reds[w][d] = s;
  __syncthreads();
  float inv = 1.0f / (reds[0][d] + reds[1][d] + reds[2][d] + reds[3][d]);
#pragma unroll
  for (int e = 0; e < 16; e++)
    PT[((size_t)bh * 64 + e0 + e) * 64 + d] = f2b(vals[e] * inv);
}

// ---------------- MT_b[o][h*64+e] = sum_d woT[o][h*64+d] * PT[e][d] ----------------
__global__ __launch_bounds__(256) void k_m(const u16* __restrict__ woT,
                                           const u16* __restrict__ PT,
                                           u16* __restrict__ MT) {
  int bh = blockIdx.x;
  int b = bh >> 4, h = bh & 15;
  int o0 = blockIdx.y * 128;
  int t = threadIdx.x, lane = t & 63, w = t >> 6;
  int r16 = lane & 15, q = lane >> 4;
  const u16* pbase = PT + (size_t)bh * 4096;
  f32x4 acc[2][4] = {};
#pragma unroll
  for (int ks = 0; ks < 2; ks++) {
    int kk = ks * 32 + q * 8;
    bf16x8 af[2], bfr[4];
#pragma unroll
    for (int i = 0; i < 2; i++)
      af[i] = *(const bf16x8*)(woT + (size_t)(o0 + w * 32 + i * 16 + r16) * 1024 + h * 64 + kk);
#pragma unroll
    for (int j = 0; j < 4; j++)
      bfr[j] = *(const bf16x8*)(pbase + (size_t)(j * 16 + r16) * 64 + kk);
#pragma unroll
    for (int i = 0; i < 2; i++)
#pragma unroll
      for (int j = 0; j < 4; j++)
        acc[i][j] = __builtin_amdgcn_mfma_f32_16x16x32_bf16(af[i], bfr[j], acc[i][j], 0, 0, 0);
  }
  u16* dst = MT + (size_t)b * 1024 * 1024;
#pragma unroll
  for (int i = 0; i < 2; i++) {
    int o = o0 + w * 32 + i * 16 + q * 4;
#pragma unroll
    for (int j = 0; j < 4; j++) {
      int e = h * 64 + j * 16 + r16;
      f32x4 a = acc[i][j];
      dst[(size_t)(o + 0) * 1024 + e] = f2b(a.x);
      dst[(size_t)(o + 1) * 1024 + e] = f2b(a.y);
      dst[(size_t)(o + 2) * 1024 + e] = f2b(a.z);
      dst[(size_t)(o + 3) * 1024 + e] = f2b(a.w);
    }
  }
}

// ---------------- GEMM2: out = vmat @ MT_b^T (fp32 out), 256x256 tiles ----
__global__ __launch_bounds__(512, 2) void k_gemm2(const u16* __restrict__ A,
                                                  const u16* __restrict__ Bt,
                                                  float* __restrict__ C) {
  __shared__ u16 lds[8 * 8192];   // 128 KiB
  int l = blockIdx.x;
  int xcd = l & 7, c = l >> 3;        // c in [0,32)
  int mt = xcd * 8 + (c & 7);
  int nt = c >> 3;                    // 0..3
  int m0 = mt * 256, n0 = nt * 256;
  int b = m0 >> 12;
  const u16* Bb = Bt + (size_t)b * 1024 * 1024;
  int t = threadIdx.x, lane = t & 63;
  int r16 = lane & 15, q = lane >> 4;
  int wr = (t >> 6) >> 2, wc = (t >> 6) & 3;
  f32x4 acc[8][4] = {};
  gemm_core256<true>(A + (size_t)m0 * 1024, Bb + (size_t)n0 * 1024, lds, t, acc);
#pragma unroll
  for (int i = 0; i < 8; i++) {
    int m = m0 + i * 32 + wr * 16 + r16;
#pragma unroll
    for (int j = 0; j < 4; j++) {
      int cc = n0 + j * 64 + wc * 16 + q * 4;
      *(f32x4*)(C + (size_t)m * 1024 + cc) = acc[i][j];
    }
  }
}

extern "C" void kernel_launch(void* const* d_in, const int* in_sizes, int n_in,
                              void* d_out, int out_size, void* d_ws, size_t ws_size,
                              hipStream_t stream) {
  const float* x     = (const float*)d_in[0];
  const float* gamma = (const float*)d_in[1];
  const float* wqkv  = (const float*)d_in[2];
  const float* temp  = (const float*)d_in[3];
  const float* wout  = (const float*)d_in[4];
  float* out = (float*)d_out;

  char* ws = (char*)d_ws;
  size_t off = 0;
  u16* xn = (u16*)(ws + off);    off += (size_t)M_TOT * 1024 * 2;   // 32M (dead after gemm1)
  u16* wqT = (u16*)(ws + off);   off += (size_t)3072 * 1024 * 2;
  u16* woT = (u16*)(ws + off);   off += (size_t)1024 * 1024 * 2;
  u16* qkT = (u16*)(ws + off);   off += (size_t)2048 * M_TOT * 2;
  u16* vmat = (u16*)(ws + off);  off += (size_t)M_TOT * 1024 * 2;
  float* sumsq = (float*)(ws + off); off += (size_t)4 * 2048 * 4;
  u16* PT = (u16*)(ws + off);    off += (size_t)64 * 64 * 64 * 2;
  u16* MT = (u16*)(ws + off);    off += (size_t)4 * 1024 * 1024 * 2;

  // Spart[16][64][64][64] fp32 (16 MB) aliases xn (32 MB), which is dead after gemm1.
  float* Spart = (float*)xn;

  // only sumsq is atomic-accumulated
  hipMemsetAsync((void*)sumsq, 0, (size_t)4 * 2048 * 4, stream);

  k_rms<<<16384, 256, 0, stream>>>(x, gamma, xn);
  dim3 cb(32, 8);
  k_castT<<<dim3(3072 / 32, 1024 / 32), cb, 0, stream>>>(wqkv, wqT, 1024, 3072);
  k_castT<<<dim3(1024 / 32, 1024 / 32), cb, 0, stream>>>(wout, woT, 1024, 1024);
  k_gemm1<<<768, 512, 0, stream>>>(xn, wqT, qkT, vmat, sumsq);
  k_attn_s<<<dim3(16, 16), 256, 0, stream>>>(qkT, Spart);
  k_softmax<<<64, 256, 0, stream>>>(Spart, sumsq, temp, PT);
  k_m<<<dim3(64, 8), 256, 0, stream>>>(woT, PT, MT);
  k_gemm2<<<1024 / 4, 512, 0, stream>>>(vmat, MT, out);
}

// Round 4
// 309.177 us; speedup vs baseline: 1.0641x; 1.0641x over previous
//
#include <hip/hip_runtime.h>
#include <stdint.h>

typedef unsigned short u16;
typedef unsigned int u32;
typedef __attribute__((ext_vector_type(8))) __bf16 bf16x8;
typedef __attribute__((ext_vector_type(4))) float f32x4;

#define M_TOT 16384   // B*N tokens
#define DIMX  1024

// RNE float->bf16 (finite inputs only)
__device__ __forceinline__ u16 f2b(float f) {
  u32 u = __builtin_bit_cast(u32, f);
  u32 r = (u + 0x7fffu + ((u >> 16) & 1u)) >> 16;
  return (u16)r;
}

__device__ __forceinline__ void gl2lds16(const void* g, void* l) {
  __builtin_amdgcn_global_load_lds((const __attribute__((address_space(1))) void*)g,
                                   (__attribute__((address_space(3))) void*)l,
                                   16, 0, 0);
}

// ---------------- RMSNorm ----------------
__global__ __launch_bounds__(256) void k_rms(const float* __restrict__ x,
                                             const float* __restrict__ gamma,
                                             u16* __restrict__ xn) {
  int row = blockIdx.x;
  int t = threadIdx.x;
  const float4* xr = (const float4*)(x + (size_t)row * DIMX);
  float4 v = xr[t];
  float ss = v.x * v.x + v.y * v.y + v.z * v.z + v.w * v.w;
#pragma unroll
  for (int o = 32; o > 0; o >>= 1) ss += __shfl_xor(ss, o, 64);
  __shared__ float wss[4];
  int w = t >> 6;
  if ((t & 63) == 0) wss[w] = ss;
  __syncthreads();
  float tot = wss[0] + wss[1] + wss[2] + wss[3];
  float scale = 32.0f / fmaxf(sqrtf(tot), 1e-12f);
  float4 g = ((const float4*)gamma)[t];
  ushort4 o4;
  o4.x = f2b(v.x * scale * g.x);
  o4.y = f2b(v.y * scale * g.y);
  o4.z = f2b(v.z * scale * g.z);
  o4.w = f2b(v.w * scale * g.w);
  ((ushort4*)xn)[(size_t)row * 256 + t] = o4;
}

// ---------------- transpose-cast ----------------
__global__ __launch_bounds__(256) void k_castT(const float* __restrict__ in,
                                               u16* __restrict__ out, int Rr, int Cc) {
  __shared__ float tile[32][33];
  int c0 = blockIdx.x * 32, r0 = blockIdx.y * 32;
  int tx = threadIdx.x, ty = threadIdx.y;
#pragma unroll
  for (int i = 0; i < 4; i++)
    tile[ty + i * 8][tx] = in[(size_t)(r0 + ty + i * 8) * Cc + c0 + tx];
  __syncthreads();
#pragma unroll
  for (int i = 0; i < 4; i++)
    out[(size_t)(c0 + ty + i * 8) * Rr + r0 + tx] = f2b(tile[tx][ty + i * 8]);
}

// ---------------- 256x256 8-wave 4-phase GEMM core, BK=64 (R2: best measured) ----
// LDS: [buf(2)][A0,A1,B0,B1][128x64 u16] = 128 KiB, double-buffered.
// Staging order (iter tt stages tile tt+1) matches READ order:
//   P0->A0, P1->B0, P2->B1, P3->A1.
// Waits: uniform vmcnt(4) at end of P0/P1/P3 (none at P2), each target issued
// >=3 phases earlier. One barrier per phase (after the wait).
// Slot swizzle s = chunk ^ (row&7) on BOTH source (pre-swizzled global addr,
// linear LDS dest) and ds_read (involution) -> conflict-free b128 reads.

template<bool SWAP>
__device__ __forceinline__ f32x4 mf(bf16x8 a, bf16x8 b, f32x4 c) {
  return SWAP ? __builtin_amdgcn_mfma_f32_16x16x32_bf16(b, a, c, 0, 0, 0)
              : __builtin_amdgcn_mfma_f32_16x16x32_bf16(a, b, c, 0, 0, 0);
}

// stage one 128x64 half-tile (16 KiB): 2 x gl2lds16 per thread (512 thr)
__device__ __forceinline__ void stage_half(const u16* __restrict__ g,
                                           u16* dst, int t, int k0) {
#pragma unroll
  for (int r = 0; r < 2; r++) {
    int chunk = r * 512 + t;
    int row = chunk >> 3;
    int cc = (chunk & 7) ^ (row & 7);            // inverse swizzle on source
    gl2lds16(g + (size_t)row * 1024 + (k0 + cc * 8),
             dst + (r * 512 + (t >> 6) * 64) * 8);  // linear, wave-uniform base
  }
}

template<bool SWAP>
__device__ __forceinline__ void gemm_core256(const u16* __restrict__ Ag,
                                             const u16* __restrict__ Bg,
                                             u16* lds, int t, f32x4 (&acc)[8][4]) {
  const int lane = t & 63;
  const int r16 = lane & 15, q = lane >> 4;
  const int s0 = (q ^ (r16 & 7)) * 8;   // u16 off of 8-elem slot, kq=0; kq=1: ^32
  const int wr = (t >> 6) >> 2, wc = (t >> 6) & 3;
  const int arow = wr * 16 + r16;
  const int brow = wc * 16 + r16;

  // prologue: tile 0 in read order A0,B0,B1,A1; wait oldest 4 (A0,B0)
  stage_half(Ag,              lds + 0,     t, 0);
  stage_half(Bg,              lds + 16384, t, 0);
  stage_half(Bg + 128 * 1024, lds + 24576, t, 0);
  stage_half(Ag + 128 * 1024, lds + 8192,  t, 0);
  asm volatile("s_waitcnt vmcnt(4)" ::: "memory");
  __builtin_amdgcn_s_barrier();

  bf16x8 af[4][2], bl[2][2], bh[2][2];
#pragma unroll 1
  for (int tt = 0; tt < 16; tt++) {
    const int bo = (tt & 1) << 15;        // buffer u16 offset 0/32768
    const int nb = bo ^ 32768;
    const int k1 = ((tt + 1) & 15) << 6;  // next K-tile (wraps: harmless re-stage)
    const u16* A0 = lds + bo;
    const u16* A1 = lds + bo + 8192;
    const u16* B0 = lds + bo + 16384;
    const u16* B1 = lds + bo + 24576;

    // ---- P0: read A_lo(8) + B_lo(4); stage A0(next); MFMA Q0 ----
#pragma unroll
    for (int i = 0; i < 4; i++) {
      af[i][0] = *(const bf16x8*)(A0 + (i * 32 + arow) * 64 + s0);
      af[i][1] = *(const bf16x8*)(A0 + (i * 32 + arow) * 64 + (s0 ^ 32));
    }
#pragma unroll
    for (int j = 0; j < 2; j++) {
      bl[j][0] = *(const bf16x8*)(B0 + (j * 64 + brow) * 64 + s0);
      bl[j][1] = *(const bf16x8*)(B0 + (j * 64 + brow) * 64 + (s0 ^ 32));
    }
    stage_half(Ag, lds + nb, t, k1);
    __builtin_amdgcn_s_setprio(1);
#pragma unroll
    for (int kq = 0; kq < 2; kq++)
#pragma unroll
      for (int i = 0; i < 4; i++)
#pragma unroll
        for (int j = 0; j < 2; j++)
          acc[i][j] = mf<SWAP>(af[i][kq], bl[j][kq], acc[i][j]);
    __builtin_amdgcn_s_setprio(0);
    asm volatile("s_waitcnt vmcnt(4)" ::: "memory");   // B.h1(cur) landed
    __builtin_amdgcn_s_barrier();

    // ---- P1: read B_hi(4); stage B0(next); MFMA Q1 ----
#pragma unroll
    for (int j = 0; j < 2; j++) {
      bh[j][0] = *(const bf16x8*)(B1 + (j * 64 + brow) * 64 + s0);
      bh[j][1] = *(const bf16x8*)(B1 + (j * 64 + brow) * 64 + (s0 ^ 32));
    }
    stage_half(Bg, lds + nb + 16384, t, k1);
    __builtin_amdgcn_s_setprio(1);
#pragma unroll
    for (int kq = 0; kq < 2; kq++)
#pragma unroll
      for (int i = 0; i < 4; i++)
#pragma unroll
        for (int j = 0; j < 2; j++)
          acc[i][2 + j] = mf<SWAP>(af[i][kq], bh[j][kq], acc[i][2 + j]);
    __builtin_amdgcn_s_setprio(0);
    asm volatile("s_waitcnt vmcnt(4)" ::: "memory");   // A.h1(cur) landed
    __builtin_amdgcn_s_barrier();

    // ---- P2: read A_hi(8); stage B1(next); MFMA Q2 ----
#pragma unroll
    for (int i = 0; i < 4; i++) {
      af[i][0] = *(const bf16x8*)(A1 + (i * 32 + arow) * 64 + s0);
      af[i][1] = *(const bf16x8*)(A1 + (i * 32 + arow) * 64 + (s0 ^ 32));
    }
    stage_half(Bg + 128 * 1024, lds + nb + 24576, t, k1);
    __builtin_amdgcn_s_setprio(1);
#pragma unroll
    for (int kq = 0; kq < 2; kq++)
#pragma unroll
      for (int i = 0; i < 4; i++)
#pragma unroll
        for (int j = 0; j < 2; j++)
          acc[4 + i][j] = mf<SWAP>(af[i][kq], bl[j][kq], acc[4 + i][j]);
    __builtin_amdgcn_s_setprio(0);
    __builtin_amdgcn_s_barrier();

    // ---- P3: stage A1(next); MFMA Q3 ----
    stage_half(Ag + 128 * 1024, lds + nb + 8192, t, k1);
    __builtin_amdgcn_s_setprio(1);
#pragma unroll
    for (int kq = 0; kq < 2; kq++)
#pragma unroll
      for (int i = 0; i < 4; i++)
#pragma unroll
        for (int j = 0; j < 2; j++)
          acc[4 + i][2 + j] = mf<SWAP>(af[i][kq], bh[j][kq], acc[4 + i][2 + j]);
    __builtin_amdgcn_s_setprio(0);
    asm volatile("s_waitcnt vmcnt(4)" ::: "memory");   // A0,B0(next) landed
    __builtin_amdgcn_s_barrier();
  }
}

// ---------------- GEMM1 merged q/k/v (256x256 tiles) ----------------
// XCD x owns mt-slab [8x, 8x+8); nt-major within chunk so ~32 concurrent
// blocks touch A 4MB + B 2MB (~L2-resident per XCD).
__global__ __launch_bounds__(512, 2) void k_gemm1(const u16* __restrict__ A,
                                                  const u16* __restrict__ Bt,   // 3072x1024
                                                  u16* __restrict__ qkT,        // 2048x16384
                                                  u16* __restrict__ vmat,       // 16384x1024
                                                  float* __restrict__ sumsq) {  // [4][2048]
  __shared__ u16 lds[8 * 8192];   // 128 KiB
  int l = blockIdx.x;
  int xcd = l & 7, c = l >> 3;        // c in [0,96)
  int mt = xcd * 8 + (c & 7);
  int nt = c >> 3;                    // 0..11
  int m0 = mt * 256, n0 = nt * 256;
  int t = threadIdx.x, lane = t & 63;
  int r16 = lane & 15, q = lane >> 4;
  int wr = (t >> 6) >> 2, wc = (t >> 6) & 3;
  f32x4 acc[8][4] = {};
  if (n0 < 2048) {
    gemm_core256<false>(A + (size_t)m0 * 1024, Bt + (size_t)n0 * 1024, lds, t, acc);
    int b = m0 >> 12;
#pragma unroll
    for (int j = 0; j < 4; j++) {
      int cc = n0 + j * 64 + wc * 16 + r16;
      float colss = 0.f;
#pragma unroll
      for (int i = 0; i < 8; i++) {
        f32x4 a = acc[i][j];
        colss += a.x * a.x + a.y * a.y + a.z * a.z + a.w * a.w;
        int m = m0 + i * 32 + wr * 16 + q * 4;
        ushort4 o4;
        o4.x = f2b(a.x); o4.y = f2b(a.y); o4.z = f2b(a.z); o4.w = f2b(a.w);
        *(ushort4*)(qkT + (size_t)cc * M_TOT + m) = o4;
      }
      colss += __shfl_xor(colss, 16, 64);
      colss += __shfl_xor(colss, 32, 64);
      if (lane < 16) atomicAdd(&sumsq[b * 2048 + cc], colss);
    }
  } else {
    gemm_core256<true>(A + (size_t)m0 * 1024, Bt + (size_t)n0 * 1024, lds, t, acc);
    int vc0 = n0 - 2048;
#pragma unroll
    for (int i = 0; i < 8; i++) {
      int m = m0 + i * 32 + wr * 16 + r16;
#pragma unroll
      for (int j = 0; j < 4; j++) {
        int cc = vc0 + j * 64 + wc * 16 + q * 4;
        f32x4 a = acc[i][j];
        ushort4 o4;
        o4.x = f2b(a.x); o4.y = f2b(a.y); o4.z = f2b(a.z); o4.w = f2b(a.w);
        *(ushort4*)(vmat + (size_t)m * 1024 + cc) = o4;
      }
    }
  }
}

// ---------------- S partials, LDS-coalesced ----------------
// grid (64 bh, 4 splits) x 256 thr.  Block: one bh, n-slice of 1024.
// Per n-tile of 256: stage q[64][256], k[64][256] into LDS via
// global_load_lds (coalesced 128B row segments, XOR slot swizzle both sides),
// 4 waves each compute a 16-row d-strip of S, acc carried across 4 tiles.
__global__ __launch_bounds__(256) void k_attn_s(const u16* __restrict__ qkT,
                                                float* __restrict__ Spart) {
  __shared__ u16 Ql[64 * 256];   // 32 KiB
  __shared__ u16 Kl[64 * 256];   // 32 KiB
  int bh = blockIdx.x, split = blockIdx.y;
  int b = bh >> 4, h = bh & 15;
  int t = threadIdx.x, lane = t & 63, w = t >> 6;
  int r16 = lane & 15, q = lane >> 4;
  const u16* qbase = qkT + (size_t)(h * 64) * M_TOT + b * 4096 + split * 1024;
  const u16* kbase = qkT + (size_t)(1024 + h * 64) * M_TOT + b * 4096 + split * 1024;
  int drow = w * 16 + r16;                 // this lane's q-row (d)
  f32x4 acc[4] = {};
#pragma unroll 1
  for (int it = 0; it < 4; it++) {
    int ncol = it * 256;
    // stage q,k tiles: 8 gl2lds16 each per thread
#pragma unroll
    for (int r = 0; r < 8; r++) {
      int ch = r * 256 + t;
      int row = ch >> 5;
      int sl = (ch & 31) ^ (row & 31);     // inverse swizzle on source
      gl2lds16(qbase + (size_t)row * M_TOT + ncol + sl * 8,
               Ql + (r * 256 + w * 64) * 8);
      gl2lds16(kbase + (size_t)row * M_TOT + ncol + sl * 8,
               Kl + (r * 256 + w * 64) * 8);
    }
    asm volatile("s_waitcnt vmcnt(0)" ::: "memory");
    __syncthreads();
#pragma unroll
    for (int it2 = 0; it2 < 8; it2++) {
      bf16x8 aq = *(const bf16x8*)(Ql + drow * 256 + (((it2 * 4 + q) ^ (drow & 31)) * 8));
#pragma unroll
      for (int j = 0; j < 4; j++) {
        int erow = j * 16 + r16;
        bf16x8 bk = *(const bf16x8*)(Kl + erow * 256 + (((it2 * 4 + q) ^ (erow & 31)) * 8));
        acc[j] = __builtin_amdgcn_mfma_f32_16x16x32_bf16(bk, aq, acc[j], 0, 0, 0);
      }
    }
    __syncthreads();
  }
  // acc[j]: d = drow (col), e = j*16 + q*4 + reg (row)
  float* Sp = Spart + ((size_t)split * 64 + bh) * 4096;
#pragma unroll
  for (int j = 0; j < 4; j++)
    *(f32x4*)(Sp + drow * 64 + j * 16 + q * 4) = acc[j];
}

// ---------------- sum 4 partials + scale + softmax -> PT[bh][e][d] bf16 ----------------
// 256 thr: thread (d = t&63, w = t>>6) owns e in [16w, 16w+16).
__global__ __launch_bounds__(256) void k_softmax(const float* __restrict__ Spart,
                                                 const float* __restrict__ sumsq,
                                                 const float* __restrict__ temp,
                                                 u16* __restrict__ PT) {
  int bh = blockIdx.x;
  int b = bh >> 4, h = bh & 15;
  int t = threadIdx.x;
  int d = t & 63, w = t >> 6;
  int e0 = w * 16;
  __shared__ float rnk[64];
  __shared__ float redm[4][64];
  __shared__ float reds[4][64];
  if (t < 64) rnk[t] = 1.0f / fmaxf(sqrtf(sumsq[b * 2048 + 1024 + h * 64 + t]), 1e-12f);
  __syncthreads();
  float nq = sqrtf(sumsq[b * 2048 + h * 64 + d]);
  float qs = 8.0f * __expf(temp[h]) / fmaxf(nq, 1e-12f);
  const float* Sp = Spart + (size_t)bh * 4096 + d * 64 + e0;
  float vals[16];
#pragma unroll
  for (int e = 0; e < 16; e += 4) {
    f32x4 v = {};
#pragma unroll
    for (int s = 0; s < 4; s++)
      v += *(const f32x4*)(Sp + (size_t)s * 64 * 4096 + e);
    vals[e + 0] = v.x; vals[e + 1] = v.y; vals[e + 2] = v.z; vals[e + 3] = v.w;
  }
  float mx = -3.0e38f;
#pragma unroll
  for (int e = 0; e < 16; e++) {
    float v = vals[e] * qs * rnk[e0 + e];
    vals[e] = v;
    mx = fmaxf(mx, v);
  }
  redm[w][d] = mx;
  __syncthreads();
  float M = fmaxf(fmaxf(redm[0][d], redm[1][d]), fmaxf(redm[2][d], redm[3][d]));
  float s = 0.f;
#pragma unroll
  for (int e = 0; e < 16; e++) {
    float v = __expf(vals[e] - M);
    vals[e] = v;
    s += v;
  }
  reds[w][d] = s;
  __syncthreads();
  float inv = 1.0f / (reds[0][d] + reds[1][d] + reds[2][d] + reds[3][d]);
#pragma unroll
  for (int e = 0; e < 16; e++)
    PT[((size_t)bh * 64 + e0 + e) * 64 + d] = f2b(vals[e] * inv);
}

// ---------------- MT_b[o][h*64+e] = sum_d woT[o][h*64+d] * PT[e][d] ----------------
__global__ __launch_bounds__(256) void k_m(const u16* __restrict__ woT,
                                           const u16* __restrict__ PT,
                                           u16* __restrict__ MT) {
  int bh = blockIdx.x;
  int b = bh >> 4, h = bh & 15;
  int o0 = blockIdx.y * 128;
  int t = threadIdx.x, lane = t & 63, w = t >> 6;
  int r16 = lane & 15, q = lane >> 4;
  const u16* pbase = PT + (size_t)bh * 4096;
  f32x4 acc[2][4] = {};
#pragma unroll
  for (int ks = 0; ks < 2; ks++) {
    int kk = ks * 32 + q * 8;
    bf16x8 af[2], bfr[4];
#pragma unroll
    for (int i = 0; i < 2; i++)
      af[i] = *(const bf16x8*)(woT + (size_t)(o0 + w * 32 + i * 16 + r16) * 1024 + h * 64 + kk);
#pragma unroll
    for (int j = 0; j < 4; j++)
      bfr[j] = *(const bf16x8*)(pbase + (size_t)(j * 16 + r16) * 64 + kk);
#pragma unroll
    for (int i = 0; i < 2; i++)
#pragma unroll
      for (int j = 0; j < 4; j++)
        acc[i][j] = __builtin_amdgcn_mfma_f32_16x16x32_bf16(af[i], bfr[j], acc[i][j], 0, 0, 0);
  }
  u16* dst = MT + (size_t)b * 1024 * 1024;
#pragma unroll
  for (int i = 0; i < 2; i++) {
    int o = o0 + w * 32 + i * 16 + q * 4;
#pragma unroll
    for (int j = 0; j < 4; j++) {
      int e = h * 64 + j * 16 + r16;
      f32x4 a = acc[i][j];
      dst[(size_t)(o + 0) * 1024 + e] = f2b(a.x);
      dst[(size_t)(o + 1) * 1024 + e] = f2b(a.y);
      dst[(size_t)(o + 2) * 1024 + e] = f2b(a.z);
      dst[(size_t)(o + 3) * 1024 + e] = f2b(a.w);
    }
  }
}

// ---------------- GEMM2: out = vmat @ MT_b^T (fp32 out), 256x256 tiles ----
__global__ __launch_bounds__(512, 2) void k_gemm2(const u16* __restrict__ A,
                                                  const u16* __restrict__ Bt,
                                                  float* __restrict__ C) {
  __shared__ u16 lds[8 * 8192];   // 128 KiB
  int l = blockIdx.x;
  int xcd = l & 7, c = l >> 3;        // c in [0,32)
  int mt = xcd * 8 + (c & 7);
  int nt = c >> 3;                    // 0..3
  int m0 = mt * 256, n0 = nt * 256;
  int b = m0 >> 12;
  const u16* Bb = Bt + (size_t)b * 1024 * 1024;
  int t = threadIdx.x, lane = t & 63;
  int r16 = lane & 15, q = lane >> 4;
  int wr = (t >> 6) >> 2, wc = (t >> 6) & 3;
  f32x4 acc[8][4] = {};
  gemm_core256<true>(A + (size_t)m0 * 1024, Bb + (size_t)n0 * 1024, lds, t, acc);
#pragma unroll
  for (int i = 0; i < 8; i++) {
    int m = m0 + i * 32 + wr * 16 + r16;
#pragma unroll
    for (int j = 0; j < 4; j++) {
      int cc = n0 + j * 64 + wc * 16 + q * 4;
      *(f32x4*)(C + (size_t)m * 1024 + cc) = acc[i][j];
    }
  }
}

extern "C" void kernel_launch(void* const* d_in, const int* in_sizes, int n_in,
                              void* d_out, int out_size, void* d_ws, size_t ws_size,
                              hipStream_t stream) {
  const float* x     = (const float*)d_in[0];
  const float* gamma = (const float*)d_in[1];
  const float* wqkv  = (const float*)d_in[2];
  const float* temp  = (const float*)d_in[3];
  const float* wout  = (const float*)d_in[4];
  float* out = (float*)d_out;

  char* ws = (char*)d_ws;
  size_t off = 0;
  u16* xn = (u16*)(ws + off);    off += (size_t)M_TOT * 1024 * 2;   // 32M (dead after gemm1)
  u16* wqT = (u16*)(ws + off);   off += (size_t)3072 * 1024 * 2;
  u16* woT = (u16*)(ws + off);   off += (size_t)1024 * 1024 * 2;
  u16* qkT = (u16*)(ws + off);   off += (size_t)2048 * M_TOT * 2;
  u16* vmat = (u16*)(ws + off);  off += (size_t)M_TOT * 1024 * 2;
  float* sumsq = (float*)(ws + off); off += (size_t)4 * 2048 * 4;
  u16* PT = (u16*)(ws + off);    off += (size_t)64 * 64 * 64 * 2;
  u16* MT = (u16*)(ws + off);    off += (size_t)4 * 1024 * 1024 * 2;

  // Spart[4][64][64][64] fp32 (4 MB) aliases xn (32 MB), dead after gemm1.
  float* Spart = (float*)xn;

  // only sumsq is atomic-accumulated
  hipMemsetAsync((void*)sumsq, 0, (size_t)4 * 2048 * 4, stream);

  k_rms<<<16384, 256, 0, stream>>>(x, gamma, xn);
  dim3 cb(32, 8);
  k_castT<<<dim3(3072 / 32, 1024 / 32), cb, 0, stream>>>(wqkv, wqT, 1024, 3072);
  k_castT<<<dim3(1024 / 32, 1024 / 32), cb, 0, stream>>>(wout, woT, 1024, 1024);
  k_gemm1<<<768, 512, 0, stream>>>(xn, wqT, qkT, vmat, sumsq);
  k_attn_s<<<dim3(64, 4), 256, 0, stream>>>(qkT, Spart);
  k_softmax<<<64, 256, 0, stream>>>(Spart, sumsq, temp, PT);
  k_m<<<dim3(64, 8), 256, 0, stream>>>(woT, PT, MT);
  k_gemm2<<<1024 / 4, 512, 0, stream>>>(vmat, MT, out);
}